// Round 2
// baseline (464.552 us; speedup 1.0000x reference)
//
#include <hip/hip_runtime.h>

typedef __attribute__((ext_vector_type(8))) __bf16 bf16x8;
typedef __attribute__((ext_vector_type(4))) float f32x4;
typedef __attribute__((ext_vector_type(4))) unsigned int u32x4;
typedef __attribute__((ext_vector_type(4))) unsigned short u16x4;
typedef __attribute__((ext_vector_type(8))) unsigned short u16x8;
typedef unsigned short u16;

static __device__ __forceinline__ u16 f2b(float f) {
    unsigned u = __builtin_bit_cast(unsigned, f);
    u = (u + 0x7FFFu + ((u >> 16) & 1u)) >> 16;
    return (u16)u;
}
static __device__ __forceinline__ float b2f(u16 u) {
    return __builtin_bit_cast(float, ((unsigned)u) << 16);
}

// ---------------- weight transpose+convert: src[K][N] f32 -> dst[N][K] bf16 ----
__global__ __launch_bounds__(256) void prep_w(
    const float* __restrict__ Wq, const float* __restrict__ Wk,
    const float* __restrict__ Wv, const float* __restrict__ Wo,
    const float* __restrict__ W1, const float* __restrict__ W2,
    u16* __restrict__ WqkvT, u16* __restrict__ WoT,
    u16* __restrict__ W1T, u16* __restrict__ W2T)
{
    const int z = blockIdx.z;
    const float* src; u16* dst; int K, N;
    if (z == 0)      { src = Wq; dst = WqkvT;             K = 512;  N = 512;  }
    else if (z == 1) { src = Wk; dst = WqkvT + 512*512;   K = 512;  N = 512;  }
    else if (z == 2) { src = Wv; dst = WqkvT + 1024*512;  K = 512;  N = 512;  }
    else if (z == 3) { src = Wo; dst = WoT;               K = 512;  N = 512;  }
    else if (z == 4) { src = W1; dst = W1T;               K = 512;  N = 2048; }
    else             { src = W2; dst = W2T;               K = 2048; N = 512;  }
    const int nt = blockIdx.x * 32, kt = blockIdx.y * 32;
    if (nt >= N || kt >= K) return;
    __shared__ float tile[32][33];
    const int tx = threadIdx.x & 31, ty = threadIdx.x >> 5;
    #pragma unroll
    for (int i = 0; i < 4; ++i)
        tile[ty + i*8][tx] = src[(size_t)(kt + ty + i*8) * N + nt + tx];
    __syncthreads();
    #pragma unroll
    for (int i = 0; i < 4; ++i)
        dst[(size_t)(nt + ty + i*8) * K + kt + tx] = f2b(tile[tx][ty + i*8]);
}

// ---------------- LayerNorm rows: [8192][512] f32 -> bf16 ----------------------
__global__ __launch_bounds__(256) void ln_rows(
    const float* __restrict__ x, const float* __restrict__ g,
    const float* __restrict__ b, u16* __restrict__ out)
{
    const int row = blockIdx.x * 4 + (threadIdx.x >> 6);
    const int lane = threadIdx.x & 63;
    const float* xr = x + (size_t)row * 512;
    f32x4 v0 = *(const f32x4*)(xr + lane * 4);
    f32x4 v1 = *(const f32x4*)(xr + 256 + lane * 4);
    float s = v0[0]+v0[1]+v0[2]+v0[3]+v1[0]+v1[1]+v1[2]+v1[3];
    #pragma unroll
    for (int o = 1; o < 64; o <<= 1) s += __shfl_xor(s, o);
    const float mu = s * (1.0f / 512.0f);
    float s2 = 0.f;
    #pragma unroll
    for (int i = 0; i < 4; ++i) { float d0 = v0[i]-mu, d1 = v1[i]-mu; s2 += d0*d0 + d1*d1; }
    #pragma unroll
    for (int o = 1; o < 64; o <<= 1) s2 += __shfl_xor(s2, o);
    const float inv = rsqrtf(s2 * (1.0f/512.0f) + 1e-5f);
    f32x4 g0 = *(const f32x4*)(g + lane*4), g1 = *(const f32x4*)(g + 256 + lane*4);
    f32x4 b0 = *(const f32x4*)(b + lane*4), b1 = *(const f32x4*)(b + 256 + lane*4);
    u16x4 p0, p1;
    #pragma unroll
    for (int i = 0; i < 4; ++i) {
        p0[i] = f2b((v0[i]-mu)*inv*g0[i] + b0[i]);
        p1[i] = f2b((v1[i]-mu)*inv*g1[i] + b1[i]);
    }
    u16* orow = out + (size_t)row * 512;
    *(u16x4*)(orow + lane*4)       = p0;
    *(u16x4*)(orow + 256 + lane*4) = p1;
}

// ---------------- GEMM: C[M][N] = A[M][K](bf16) * BT[N][K](bf16)^T + epilogue --
// FLAGS: 1=bias, 2=residual(f32), 4=relu, 8=store f32 (else bf16)
template<int FLAGS>
__global__ __launch_bounds__(256) void gemm_bt(
    const u16* __restrict__ A, const u16* __restrict__ BT,
    const int N, const int K,
    const float* __restrict__ bias, const float* __restrict__ res,
    void* __restrict__ outv)
{
    __shared__ __attribute__((aligned(16))) u16 As[128*32];
    __shared__ __attribute__((aligned(16))) u16 Bs[128*32];
    const int tid = threadIdx.x, lane = tid & 63, w = tid >> 6;
    const int wr = w >> 1, wc = w & 1;
    const int m0 = blockIdx.y << 7, n0 = blockIdx.x << 7;
    const int g = lane >> 4, c = lane & 15;
    const f32x4 fz = {0.f, 0.f, 0.f, 0.f};

    f32x4 acc[4][4];
    #pragma unroll
    for (int m = 0; m < 4; ++m)
      #pragma unroll
      for (int n = 0; n < 4; ++n) acc[m][n] = fz;

    const int srow = tid >> 2, sch = tid & 3;
    const int sOff0 = srow*32 + (((sch*16) ^ ((srow&3)<<4)) >> 1);
    const int sOff1 = sOff0 + 64*32;
    const u16* Ag = A  + (size_t)(m0 + srow)*K + sch*8;
    const u16* Bg = BT + (size_t)(n0 + srow)*K + sch*8;
    const size_t rstep = (size_t)64 * K;

    const int nkt = K >> 5;
    for (int kt = 0; kt < nkt; ++kt) {
        const int k0 = kt << 5;
        u32x4 a0 = *(const u32x4*)(Ag + k0);
        u32x4 a1 = *(const u32x4*)(Ag + rstep + k0);
        u32x4 b0 = *(const u32x4*)(Bg + k0);
        u32x4 b1 = *(const u32x4*)(Bg + rstep + k0);
        *(u32x4*)(As + sOff0) = a0;
        *(u32x4*)(As + sOff1) = a1;
        *(u32x4*)(Bs + sOff0) = b0;
        *(u32x4*)(Bs + sOff1) = b1;
        __syncthreads();
        bf16x8 af[4], bfr[4];
        #pragma unroll
        for (int m = 0; m < 4; ++m) {
            const int row = wr*64 + m*16 + c;
            af[m] = *(const bf16x8*)(As + row*32 + (((g*16) ^ ((row&3)<<4)) >> 1));
        }
        #pragma unroll
        for (int n = 0; n < 4; ++n) {
            const int row = wc*64 + n*16 + c;
            bfr[n] = *(const bf16x8*)(Bs + row*32 + (((g*16) ^ ((row&3)<<4)) >> 1));
        }
        #pragma unroll
        for (int m = 0; m < 4; ++m)
          #pragma unroll
          for (int n = 0; n < 4; ++n)
            acc[m][n] = __builtin_amdgcn_mfma_f32_16x16x32_bf16(af[m], bfr[n], acc[m][n], 0, 0, 0);
        __syncthreads();
    }

    #pragma unroll
    for (int m = 0; m < 4; ++m) {
        const int row = m0 + wr*64 + m*16 + 4*g;
        #pragma unroll
        for (int n = 0; n < 4; ++n) {
            const int col = n0 + wc*64 + n*16 + c;
            const float bv = (FLAGS & 1) ? bias[col] : 0.0f;
            #pragma unroll
            for (int r = 0; r < 4; ++r) {
                float v = acc[m][n][r] + bv;
                if (FLAGS & 2) v += res[(size_t)(row + r)*N + col];
                if (FLAGS & 4) v = fmaxf(v, 0.0f);
                if (FLAGS & 8) ((float*)outv)[(size_t)(row + r)*N + col] = v;
                else           ((u16*)outv)[(size_t)(row + r)*N + col] = f2b(v);
            }
        }
    }
}

// ---------------- V transpose: qkv cols [1024..1536) -> vT[B*H*64][4096] ------
__global__ __launch_bounds__(256) void transpose_v(
    const u16* __restrict__ qkv, u16* __restrict__ vT)
{
    const int b = blockIdx.z;
    const int t0 = blockIdx.x * 32, c0 = blockIdx.y * 32;
    __shared__ u16 tile[32][33];
    const int tx = threadIdx.x & 31, ty = threadIdx.x >> 5;
    #pragma unroll
    for (int i = 0; i < 4; ++i)
        tile[ty + i*8][tx] =
            qkv[(size_t)(b*4096 + t0 + ty + i*8)*1536 + 1024 + c0 + tx];
    __syncthreads();
    #pragma unroll
    for (int i = 0; i < 4; ++i)
        vT[(size_t)(b*512 + c0 + ty + i*8)*4096 + t0 + tx] = tile[tx][ty + i*8];
}

// ---------------- causal flash attention, split-kv, static max -----------------
// grid (160, B*H); 256 thr = 4 waves; wave w owns q rows [64q+16w, +16)
// chunk id i -> (q-tile q, kv-chunk c); chunk covers 64-kv tiles [16c, min(16c+16, q+1))
// Writes UNNORMALIZED partial O (bf16 [64][64]) + partial l (f32 [64]) per chunk.
__global__ __launch_bounds__(256) void attn_fwd(
    const u16* __restrict__ qkv, const u16* __restrict__ vT, u16* __restrict__ part)
{
    const int bh = blockIdx.y, b = bh >> 3, h = bh & 7;
    const int i = blockIdx.x;
    int q, cch;
    if (i < 16)      { q = i;                       cch = 0; }
    else if (i < 48) { int j = i-16; q = 16 + (j>>1); cch = j & 1; }
    else if (i < 96) { int j = i-48; int d = j/3; q = 32 + d; cch = j - 3*d; }
    else             { int j = i-96; q = 48 + (j>>2); cch = j & 3; }
    const int t0 = cch*16;
    const int t1e = t0 + 16, t1 = (t1e < q+1) ? t1e : q+1;

    const int tid = threadIdx.x, lane = tid & 63, w = tid >> 6;
    const int g = lane >> 4, c16 = lane & 15;
    __shared__ __attribute__((aligned(16))) u16 Ps[4][16*72];

    const u16* qp  = qkv + (size_t)b*4096*1536 + h*64;
    const u16* kp  = qp + 512;
    const u16* vtp = vT + (size_t)bh*64*4096;

    const int q0w = q*64 + w*16;
    const bf16x8 qf0 = *(const bf16x8*)(qp + (size_t)(q0w + c16)*1536 + g*8);
    const bf16x8 qf1 = *(const bf16x8*)(qp + (size_t)(q0w + c16)*1536 + 32 + g*8);

    const f32x4 fz = {0.f, 0.f, 0.f, 0.f};
    f32x4 oacc[4] = {fz, fz, fz, fz};
    float lsum[4] = {0.f, 0.f, 0.f, 0.f};
    const float scale = 0.04419417382415922f; // 512^-0.5
    u16* Pw = &Ps[w][0];

    for (int t = t0; t < t1; ++t) {
        const int kv0 = t << 6;
        // ---- QK^T: S[16q x 64kv], K fragments direct from global (L2) ----
        f32x4 s[4];
        #pragma unroll
        for (int sub = 0; sub < 4; ++sub) {
            const u16* kr = kp + (size_t)(kv0 + sub*16 + c16)*1536 + g*8;
            bf16x8 kb0 = *(const bf16x8*)(kr);
            bf16x8 kb1 = *(const bf16x8*)(kr + 32);
            f32x4 sv = fz;
            sv = __builtin_amdgcn_mfma_f32_16x16x32_bf16(qf0, kb0, sv, 0, 0, 0);
            sv = __builtin_amdgcn_mfma_f32_16x16x32_bf16(qf1, kb1, sv, 0, 0, 0);
            s[sub] = sv;
        }
        // ---- prefetch V fragments (independent of softmax) ----
        bf16x8 vb[4][2];
        #pragma unroll
        for (int dt = 0; dt < 4; ++dt) {
            const u16* vr = vtp + (size_t)(dt*16 + c16)*4096 + kv0 + g*8;
            vb[dt][0] = *(const bf16x8*)(vr);
            vb[dt][1] = *(const bf16x8*)(vr + 32);
        }
        // ---- softmax numerator, static max = 0, deferred denominator ----
        const bool full = (kv0 + 63 <= q0w);
        if (full) {
            #pragma unroll
            for (int sub = 0; sub < 4; ++sub)
              #pragma unroll
              for (int r = 0; r < 4; ++r) {
                  float p = __expf(s[sub][r] * scale);
                  lsum[r] += p;
                  Pw[(4*g + r)*72 + sub*16 + c16] = f2b(p);
              }
        } else {
            #pragma unroll
            for (int sub = 0; sub < 4; ++sub)
              #pragma unroll
              for (int r = 0; r < 4; ++r) {
                  const int qi = q0w + 4*g + r;
                  const int kv = kv0 + sub*16 + c16;
                  float p = (kv <= qi) ? __expf(s[sub][r] * scale) : 0.0f;
                  lsum[r] += p;
                  Pw[(4*g + r)*72 + sub*16 + c16] = f2b(p);
              }
        }
        // ---- P bounce (per-wave LDS, wave-ordered: no barrier) ----
        const bf16x8 pa0 = *(const bf16x8*)(Pw + c16*72 + g*8);
        const bf16x8 pa1 = *(const bf16x8*)(Pw + c16*72 + 32 + g*8);
        // ---- PV ----
        #pragma unroll
        for (int dt = 0; dt < 4; ++dt) {
            oacc[dt] = __builtin_amdgcn_mfma_f32_16x16x32_bf16(pa0, vb[dt][0], oacc[dt], 0, 0, 0);
            oacc[dt] = __builtin_amdgcn_mfma_f32_16x16x32_bf16(pa1, vb[dt][1], oacc[dt], 0, 0, 0);
        }
    }

    // one reduction per block (not per tile): sum l across the 16 c-lanes
    #pragma unroll
    for (int r = 0; r < 4; ++r) {
        float v = lsum[r];
        v += __shfl_xor(v, 1); v += __shfl_xor(v, 2);
        v += __shfl_xor(v, 4); v += __shfl_xor(v, 8);
        lsum[r] = v;
    }

    u16* onum = part + (size_t)(bh*160 + i) * 4224;   // 8448 B/slot = 4224 u16
    float* lout = (float*)(onum + 4096);
    const int qloc = w*16 + 4*g;
    #pragma unroll
    for (int r = 0; r < 4; ++r) {
        #pragma unroll
        for (int dt = 0; dt < 4; ++dt)
            onum[(qloc + r)*64 + dt*16 + c16] = f2b(oacc[dt][r]);
        if (c16 == 0) lout[qloc + r] = lsum[r];
    }
}

// ---------------- merge split-kv partials, normalize, write ATT ---------------
__global__ __launch_bounds__(256) void attn_merge(
    const u16* __restrict__ part, u16* __restrict__ att)
{
    const int q = blockIdx.x, bh = blockIdx.y, b = bh >> 3, h = bh & 7;
    int start, n;
    if (q < 16)      { start = q;               n = 1; }
    else if (q < 32) { start = 16 + 2*(q-16);   n = 2; }
    else if (q < 48) { start = 48 + 3*(q-32);   n = 3; }
    else             { start = 96 + 4*(q-48);   n = 4; }
    const int t = threadIdx.x;
    const int row = t >> 2, c0 = (t & 3) * 16;
    float acc[16];
    #pragma unroll
    for (int j = 0; j < 16; ++j) acc[j] = 0.f;
    float lt = 0.f;
    const u16* p0 = part + (size_t)(bh*160 + start) * 4224;
    for (int ci = 0; ci < n; ++ci) {
        const u16* pc = p0 + (size_t)ci * 4224;
        lt += ((const float*)(pc + 4096))[row];
        u16x8 a = *(const u16x8*)(pc + row*64 + c0);
        u16x8 bq = *(const u16x8*)(pc + row*64 + c0 + 8);
        #pragma unroll
        for (int j = 0; j < 8; ++j) { acc[j] += b2f(a[j]); acc[8+j] += b2f(bq[j]); }
    }
    const float inv = 1.0f / lt;
    u16x8 o1, o2;
    #pragma unroll
    for (int j = 0; j < 8; ++j) { o1[j] = f2b(acc[j]*inv); o2[j] = f2b(acc[8+j]*inv); }
    u16* dst = att + (size_t)(b*4096 + q*64 + row)*512 + h*64 + c0;
    *(u16x8*)dst = o1;
    *(u16x8*)(dst + 8) = o2;
}

// -------------------------------------------------------------------------------
extern "C" void kernel_launch(void* const* d_in, const int* in_sizes, int n_in,
                              void* d_out, int out_size, void* d_ws, size_t ws_size,
                              hipStream_t stream)
{
    (void)in_sizes; (void)n_in; (void)out_size; (void)ws_size;
    const float* x   = (const float*)d_in[0];
    const float* Wq  = (const float*)d_in[1];
    const float* Wk  = (const float*)d_in[2];
    const float* Wv  = (const float*)d_in[3];
    const float* Wo  = (const float*)d_in[4];
    const float* bo  = (const float*)d_in[5];
    const float* W1  = (const float*)d_in[6];
    const float* b1  = (const float*)d_in[7];
    const float* W2  = (const float*)d_in[8];
    const float* b2  = (const float*)d_in[9];
    const float* g1  = (const float*)d_in[10];
    const float* be1 = (const float*)d_in[11];
    const float* g2  = (const float*)d_in[12];
    const float* be2 = (const float*)d_in[13];

    char* ws = (char*)d_ws;
    u16*   WqkvT = (u16*)(ws + 0);
    u16*   WoT   = (u16*)(ws + 1572864);
    u16*   W1T   = (u16*)(ws + 2097152);
    u16*   W2T   = (u16*)(ws + 4194304);
    u16*   H     = (u16*)(ws + 6291456);    // ln1/ln2 out [8192][512] bf16
    u16*   PART  = (u16*)(ws + 6291456);    // attn partials (reuses dead H+X2 region
                                            //  during attention: H rewritten by ln2,
                                            //  X2 written after merge). 2560*8448B
    float* X2    = (float*)(ws + 14680064); // post-attention residual (f32)
    u16*   QKV   = (u16*)(ws + 31457280);   // [8192][1536]
    u16*   VT    = (u16*)(ws + 56623104);   // [1024][4096]
    u16*   ATT   = (u16*)(ws + 65011712);   // [8192][512]
    u16*   F1    = (u16*)(ws + 31457280);   // [8192][2048], reuses QKV+VT

    prep_w<<<dim3(64, 64, 6), 256, 0, stream>>>(Wq, Wk, Wv, Wo, W1, W2,
                                                WqkvT, WoT, W1T, W2T);
    ln_rows<<<2048, 256, 0, stream>>>(x, g1, be1, H);
    gemm_bt<0><<<dim3(12, 64), 256, 0, stream>>>(H, WqkvT, 1536, 512,
                                                 nullptr, nullptr, QKV);
    transpose_v<<<dim3(128, 16, 2), 256, 0, stream>>>(QKV, VT);
    attn_fwd<<<dim3(160, 16), 256, 0, stream>>>(QKV, VT, PART);
    attn_merge<<<dim3(64, 16), 256, 0, stream>>>(PART, ATT);
    gemm_bt<11><<<dim3(4, 64), 256, 0, stream>>>(ATT, WoT, 512, 512,
                                                 bo, x, X2);
    ln_rows<<<2048, 256, 0, stream>>>(X2, g2, be2, H);
    gemm_bt<5><<<dim3(16, 64), 256, 0, stream>>>(H, W1T, 2048, 512,
                                                 b1, nullptr, F1);
    gemm_bt<11><<<dim3(4, 64), 256, 0, stream>>>(F1, W2T, 512, 2048,
                                                 b2, X2, (float*)d_out);
}

// Round 3
// 233.980 us; speedup vs baseline: 1.9854x; 1.9854x over previous
//
#include <hip/hip_runtime.h>

typedef __attribute__((ext_vector_type(8))) __bf16 bf16x8;
typedef __attribute__((ext_vector_type(4))) float f32x4;
typedef __attribute__((ext_vector_type(4))) unsigned int u32x4;
typedef __attribute__((ext_vector_type(4))) unsigned short u16x4;
typedef __attribute__((ext_vector_type(8))) unsigned short u16x8;
typedef unsigned short u16;

static __device__ __forceinline__ u16 f2b(float f) {
    unsigned u = __builtin_bit_cast(unsigned, f);
    u = (u + 0x7FFFu + ((u >> 16) & 1u)) >> 16;
    return (u16)u;
}
static __device__ __forceinline__ float b2f(u16 u) {
    return __builtin_bit_cast(float, ((unsigned)u) << 16);
}

// async global->LDS, 16B per lane; LDS dest = wave-uniform base + lane*16
static __device__ __forceinline__ void gload16(const u16* g, u16* l) {
    __builtin_amdgcn_global_load_lds(
        (const __attribute__((address_space(1))) unsigned int*)g,
        (__attribute__((address_space(3))) unsigned int*)l, 16, 0, 0);
}

// ---------------- weight transpose+convert: src[K][N] f32 -> dst[N][K] bf16 ----
__global__ __launch_bounds__(256) void prep_w(
    const float* __restrict__ Wq, const float* __restrict__ Wk,
    const float* __restrict__ Wv, const float* __restrict__ Wo,
    const float* __restrict__ W1, const float* __restrict__ W2,
    u16* __restrict__ WqkvT, u16* __restrict__ WoT,
    u16* __restrict__ W1T, u16* __restrict__ W2T)
{
    const int z = blockIdx.z;
    const float* src; u16* dst; int K, N;
    if (z == 0)      { src = Wq; dst = WqkvT;             K = 512;  N = 512;  }
    else if (z == 1) { src = Wk; dst = WqkvT + 512*512;   K = 512;  N = 512;  }
    else if (z == 2) { src = Wv; dst = WqkvT + 1024*512;  K = 512;  N = 512;  }
    else if (z == 3) { src = Wo; dst = WoT;               K = 512;  N = 512;  }
    else if (z == 4) { src = W1; dst = W1T;               K = 512;  N = 2048; }
    else             { src = W2; dst = W2T;               K = 2048; N = 512;  }
    const int nt = blockIdx.x * 32, kt = blockIdx.y * 32;
    if (nt >= N || kt >= K) return;
    __shared__ float tile[32][33];
    const int tx = threadIdx.x & 31, ty = threadIdx.x >> 5;
    #pragma unroll
    for (int i = 0; i < 4; ++i)
        tile[ty + i*8][tx] = src[(size_t)(kt + ty + i*8) * N + nt + tx];
    __syncthreads();
    #pragma unroll
    for (int i = 0; i < 4; ++i)
        dst[(size_t)(nt + ty + i*8) * K + kt + tx] = f2b(tile[tx][ty + i*8]);
}

// ---------------- LayerNorm rows: [8192][512] f32 -> bf16 ----------------------
__global__ __launch_bounds__(256) void ln_rows(
    const float* __restrict__ x, const float* __restrict__ g,
    const float* __restrict__ b, u16* __restrict__ out)
{
    const int row = blockIdx.x * 4 + (threadIdx.x >> 6);
    const int lane = threadIdx.x & 63;
    const float* xr = x + (size_t)row * 512;
    f32x4 v0 = *(const f32x4*)(xr + lane * 4);
    f32x4 v1 = *(const f32x4*)(xr + 256 + lane * 4);
    float s = v0[0]+v0[1]+v0[2]+v0[3]+v1[0]+v1[1]+v1[2]+v1[3];
    #pragma unroll
    for (int o = 1; o < 64; o <<= 1) s += __shfl_xor(s, o);
    const float mu = s * (1.0f / 512.0f);
    float s2 = 0.f;
    #pragma unroll
    for (int i = 0; i < 4; ++i) { float d0 = v0[i]-mu, d1 = v1[i]-mu; s2 += d0*d0 + d1*d1; }
    #pragma unroll
    for (int o = 1; o < 64; o <<= 1) s2 += __shfl_xor(s2, o);
    const float inv = rsqrtf(s2 * (1.0f/512.0f) + 1e-5f);
    f32x4 g0 = *(const f32x4*)(g + lane*4), g1 = *(const f32x4*)(g + 256 + lane*4);
    f32x4 b0 = *(const f32x4*)(b + lane*4), b1 = *(const f32x4*)(b + 256 + lane*4);
    u16x4 p0, p1;
    #pragma unroll
    for (int i = 0; i < 4; ++i) {
        p0[i] = f2b((v0[i]-mu)*inv*g0[i] + b0[i]);
        p1[i] = f2b((v1[i]-mu)*inv*g1[i] + b1[i]);
    }
    u16* orow = out + (size_t)row * 512;
    *(u16x4*)(orow + lane*4)       = p0;
    *(u16x4*)(orow + 256 + lane*4) = p1;
}

// ---------------- GEMM: C[M][N] = A[M][K](bf16) * BT[N][K](bf16)^T + epilogue --
// FLAGS: 1=bias, 2=residual(f32), 4=relu, 8=store f32 (else bf16)
// Staging via global_load_lds: linear LDS dest, source chunk pre-swizzled with
// the same involution (chunk ^= row&3) the read side uses -> reads unchanged.
template<int FLAGS>
__global__ __launch_bounds__(256) void gemm_bt(
    const u16* __restrict__ A, const u16* __restrict__ BT,
    const int N, const int K,
    const float* __restrict__ bias, const float* __restrict__ res,
    void* __restrict__ outv)
{
    __shared__ __attribute__((aligned(16))) u16 As[128*32];
    __shared__ __attribute__((aligned(16))) u16 Bs[128*32];
    const int tid = threadIdx.x, lane = tid & 63, w = tid >> 6;
    const int wr = w >> 1, wc = w & 1;
    const int m0 = blockIdx.y << 7, n0 = blockIdx.x << 7;
    const int g = lane >> 4, c = lane & 15;
    const f32x4 fz = {0.f, 0.f, 0.f, 0.f};

    f32x4 acc[4][4];
    #pragma unroll
    for (int m = 0; m < 4; ++m)
      #pragma unroll
      for (int n = 0; n < 4; ++n) acc[m][n] = fz;

    // staging geometry: chunk ci = tid (+256): row = ci>>2, col-chunk = ci&3,
    // source chunk = (ci&3) ^ (row&3); LDS element base per wave/call.
    const int srow = tid >> 2;
    const int scs = (((tid & 3) ^ (srow & 3)) * 8);
    const u16* Ag = A  + (size_t)(m0 + srow)*K + scs;
    const u16* Bg = BT + (size_t)(n0 + srow)*K + scs;
    const size_t rstep = (size_t)64 * K;
    u16* AsW = As + w*512;
    u16* BsW = Bs + w*512;

    const int nkt = K >> 5;
    for (int kt = 0; kt < nkt; ++kt) {
        const int k0 = kt << 5;
        gload16(Ag + k0,         AsW);
        gload16(Ag + rstep + k0, AsW + 2048);
        gload16(Bg + k0,         BsW);
        gload16(Bg + rstep + k0, BsW + 2048);
        __syncthreads();
        bf16x8 af[4], bfr[4];
        #pragma unroll
        for (int m = 0; m < 4; ++m) {
            const int row = wr*64 + m*16 + c;
            af[m] = *(const bf16x8*)(As + row*32 + (((g*16) ^ ((row&3)<<4)) >> 1));
        }
        #pragma unroll
        for (int n = 0; n < 4; ++n) {
            const int row = wc*64 + n*16 + c;
            bfr[n] = *(const bf16x8*)(Bs + row*32 + (((g*16) ^ ((row&3)<<4)) >> 1));
        }
        #pragma unroll
        for (int m = 0; m < 4; ++m)
          #pragma unroll
          for (int n = 0; n < 4; ++n)
            acc[m][n] = __builtin_amdgcn_mfma_f32_16x16x32_bf16(af[m], bfr[n], acc[m][n], 0, 0, 0);
        __syncthreads();
    }

    #pragma unroll
    for (int m = 0; m < 4; ++m) {
        const int row = m0 + wr*64 + m*16 + 4*g;
        #pragma unroll
        for (int n = 0; n < 4; ++n) {
            const int col = n0 + wc*64 + n*16 + c;
            const float bv = (FLAGS & 1) ? bias[col] : 0.0f;
            #pragma unroll
            for (int r = 0; r < 4; ++r) {
                float v = acc[m][n][r] + bv;
                if (FLAGS & 2) v += res[(size_t)(row + r)*N + col];
                if (FLAGS & 4) v = fmaxf(v, 0.0f);
                if (FLAGS & 8) ((float*)outv)[(size_t)(row + r)*N + col] = v;
                else           ((u16*)outv)[(size_t)(row + r)*N + col] = f2b(v);
            }
        }
    }
}

// ---------------- V transpose: qkv cols [1024..1536) -> vT[B*H*64][4096] ------
__global__ __launch_bounds__(256) void transpose_v(
    const u16* __restrict__ qkv, u16* __restrict__ vT)
{
    const int b = blockIdx.z;
    const int t0 = blockIdx.x * 32, c0 = blockIdx.y * 32;
    __shared__ u16 tile[32][33];
    const int tx = threadIdx.x & 31, ty = threadIdx.x >> 5;
    #pragma unroll
    for (int i = 0; i < 4; ++i)
        tile[ty + i*8][tx] =
            qkv[(size_t)(b*4096 + t0 + ty + i*8)*1536 + 1024 + c0 + tx];
    __syncthreads();
    #pragma unroll
    for (int i = 0; i < 4; ++i)
        vT[(size_t)(b*512 + c0 + ty + i*8)*4096 + t0 + tx] = tile[tx][ty + i*8];
}

// ---------------- causal flash attention, split-kv, static max -----------------
// grid (160, B*H); 4 waves; wave w owns q rows [64q+16w, +16).
// K/V tiles (64 kv x 64 d) double-buffered in LDS via global_load_lds with
// pre-swizzled source (chunk ^= row&7); compute tile t overlaps DMA of t+1.
__global__ __launch_bounds__(256) void attn_fwd(
    const u16* __restrict__ qkv, const u16* __restrict__ vT, u16* __restrict__ part)
{
    const int bh = blockIdx.y, b = bh >> 3, h = bh & 7;
    const int i = blockIdx.x;
    int q, cch;
    if (i < 16)      { q = i;                       cch = 0; }
    else if (i < 48) { int j = i-16; q = 16 + (j>>1); cch = j & 1; }
    else if (i < 96) { int j = i-48; int d = j/3; q = 32 + d; cch = j - 3*d; }
    else             { int j = i-96; q = 48 + (j>>2); cch = j & 3; }
    const int t0 = cch*16;
    const int t1e = t0 + 16, t1 = (t1e < q+1) ? t1e : q+1;

    const int tid = threadIdx.x, lane = tid & 63, w = tid >> 6;
    const int g = lane >> 4, c16 = lane & 15;
    __shared__ __attribute__((aligned(16))) u16 Ks[2][4096];
    __shared__ __attribute__((aligned(16))) u16 Vs[2][4096];
    __shared__ __attribute__((aligned(16))) u16 Ps[4][16*72];

    const u16* qp  = qkv + (size_t)b*4096*1536 + h*64;
    const u16* kp  = qp + 512;
    const u16* vtp = vT + (size_t)bh*64*4096;

    // staging geometry: chunk ci = tid (+256): row = ci>>3, src chunk ^= row&7
    const int srow = tid >> 3;                       // 0..31 (call1: +32)
    const int scs  = (((tid & 7) ^ (srow & 7)) * 8); // elements
    const u16* kg0 = kp + (size_t)srow*1536 + scs;   // + kv0*1536
    const u16* kg1 = kg0 + (size_t)32*1536;
    const u16* vg0 = vtp + (size_t)srow*4096 + scs;  // + kv0
    const u16* vg1 = vg0 + (size_t)32*4096;
    u16* KsW0 = &Ks[0][0] + w*512;  u16* VsW0 = &Vs[0][0] + w*512;
    u16* KsW1 = &Ks[1][0] + w*512;  u16* VsW1 = &Vs[1][0] + w*512;

    const int q0w = q*64 + w*16;
    const bf16x8 qf0 = *(const bf16x8*)(qp + (size_t)(q0w + c16)*1536 + g*8);
    const bf16x8 qf1 = *(const bf16x8*)(qp + (size_t)(q0w + c16)*1536 + 32 + g*8);

    const f32x4 fz = {0.f, 0.f, 0.f, 0.f};
    f32x4 oacc[4] = {fz, fz, fz, fz};
    float lsum[4] = {0.f, 0.f, 0.f, 0.f};
    const float scale = 0.04419417382415922f; // 512^-0.5
    u16* Pw = &Ps[w][0];

    // fragment read offsets (swizzled layout): row*64 + ((j ^ (row&7))*8)
    const int rA = c16;                // row&7 == c16&7 for all sub/dt
    const int jx = (g ^ (rA & 7)) * 8, jy = ((4+g) ^ (rA & 7)) * 8;

    // prologue: stage tile t0 into buf 0
    {
        const size_t kvo = (size_t)(t0 << 6);
        gload16(kg0 + kvo*1536, KsW0); gload16(kg1 + kvo*1536, KsW0 + 2048);
        gload16(vg0 + kvo,      VsW0); gload16(vg1 + kvo,      VsW0 + 2048);
    }
    __syncthreads();

    int buf = 0;
    for (int t = t0; t < t1; ++t) {
        if (t + 1 < t1) {
            const size_t kvo = (size_t)((t+1) << 6);
            u16* kd = buf ? KsW0 : KsW1;
            u16* vd = buf ? VsW0 : VsW1;
            gload16(kg0 + kvo*1536, kd); gload16(kg1 + kvo*1536, kd + 2048);
            gload16(vg0 + kvo,      vd); gload16(vg1 + kvo,      vd + 2048);
        }
        const u16* Kb = &Ks[buf][0];
        const u16* Vb = &Vs[buf][0];
        const int kv0 = t << 6;

        // ---- QK^T ----
        f32x4 s[4];
        #pragma unroll
        for (int sub = 0; sub < 4; ++sub) {
            const int ro = (sub*16 + c16) * 64;
            bf16x8 kb0 = *(const bf16x8*)(Kb + ro + jx);
            bf16x8 kb1 = *(const bf16x8*)(Kb + ro + jy);
            f32x4 sv = fz;
            sv = __builtin_amdgcn_mfma_f32_16x16x32_bf16(qf0, kb0, sv, 0, 0, 0);
            sv = __builtin_amdgcn_mfma_f32_16x16x32_bf16(qf1, kb1, sv, 0, 0, 0);
            s[sub] = sv;
        }
        // ---- softmax numerator, static max = 0, deferred denominator ----
        const bool fullt = (kv0 + 63 <= q0w);
        if (fullt) {
            #pragma unroll
            for (int sub = 0; sub < 4; ++sub)
              #pragma unroll
              for (int r = 0; r < 4; ++r) {
                  float p = __expf(s[sub][r] * scale);
                  lsum[r] += p;
                  Pw[(4*g + r)*72 + sub*16 + c16] = f2b(p);
              }
        } else {
            #pragma unroll
            for (int sub = 0; sub < 4; ++sub)
              #pragma unroll
              for (int r = 0; r < 4; ++r) {
                  const int qi = q0w + 4*g + r;
                  const int kv = kv0 + sub*16 + c16;
                  float p = (kv <= qi) ? __expf(s[sub][r] * scale) : 0.0f;
                  lsum[r] += p;
                  Pw[(4*g + r)*72 + sub*16 + c16] = f2b(p);
              }
        }
        // ---- P bounce (per-wave LDS, wave-ordered: no barrier) ----
        const bf16x8 pa0 = *(const bf16x8*)(Pw + c16*72 + g*8);
        const bf16x8 pa1 = *(const bf16x8*)(Pw + c16*72 + 32 + g*8);
        // ---- PV ----
        #pragma unroll
        for (int dt = 0; dt < 4; ++dt) {
            const int ro = (dt*16 + c16) * 64;
            bf16x8 vb0 = *(const bf16x8*)(Vb + ro + jx);
            bf16x8 vb1 = *(const bf16x8*)(Vb + ro + jy);
            oacc[dt] = __builtin_amdgcn_mfma_f32_16x16x32_bf16(pa0, vb0, oacc[dt], 0, 0, 0);
            oacc[dt] = __builtin_amdgcn_mfma_f32_16x16x32_bf16(pa1, vb1, oacc[dt], 0, 0, 0);
        }
        __syncthreads();   // drains DMA (vmcnt) + guards buf reuse
        buf ^= 1;
    }

    #pragma unroll
    for (int r = 0; r < 4; ++r) {
        float v = lsum[r];
        v += __shfl_xor(v, 1); v += __shfl_xor(v, 2);
        v += __shfl_xor(v, 4); v += __shfl_xor(v, 8);
        lsum[r] = v;
    }

    u16* onum = part + (size_t)(bh*160 + i) * 4224;   // 8448 B/slot
    float* lout = (float*)(onum + 4096);
    const int qloc = w*16 + 4*g;
    #pragma unroll
    for (int r = 0; r < 4; ++r) {
        #pragma unroll
        for (int dt = 0; dt < 4; ++dt)
            onum[(qloc + r)*64 + dt*16 + c16] = f2b(oacc[dt][r]);
        if (c16 == 0) lout[qloc + r] = lsum[r];
    }
}

// ---------------- merge split-kv partials, normalize, write ATT ---------------
__global__ __launch_bounds__(256) void attn_merge(
    const u16* __restrict__ part, u16* __restrict__ att)
{
    const int q = blockIdx.x, bh = blockIdx.y, b = bh >> 3, h = bh & 7;
    int start, n;
    if (q < 16)      { start = q;               n = 1; }
    else if (q < 32) { start = 16 + 2*(q-16);   n = 2; }
    else if (q < 48) { start = 48 + 3*(q-32);   n = 3; }
    else             { start = 96 + 4*(q-48);   n = 4; }
    const int t = threadIdx.x;
    const int row = t >> 2, c0 = (t & 3) * 16;
    float acc[16];
    #pragma unroll
    for (int j = 0; j < 16; ++j) acc[j] = 0.f;
    float lt = 0.f;
    const u16* p0 = part + (size_t)(bh*160 + start) * 4224;
    for (int ci = 0; ci < n; ++ci) {
        const u16* pc = p0 + (size_t)ci * 4224;
        lt += ((const float*)(pc + 4096))[row];
        u16x8 a = *(const u16x8*)(pc + row*64 + c0);
        u16x8 bq = *(const u16x8*)(pc + row*64 + c0 + 8);
        #pragma unroll
        for (int j = 0; j < 8; ++j) { acc[j] += b2f(a[j]); acc[8+j] += b2f(bq[j]); }
    }
    const float inv = 1.0f / lt;
    u16x8 o1, o2;
    #pragma unroll
    for (int j = 0; j < 8; ++j) { o1[j] = f2b(acc[j]*inv); o2[j] = f2b(acc[8+j]*inv); }
    u16* dst = att + (size_t)(b*4096 + q*64 + row)*512 + h*64 + c0;
    *(u16x8*)dst = o1;
    *(u16x8*)(dst + 8) = o2;
}

// -------------------------------------------------------------------------------
extern "C" void kernel_launch(void* const* d_in, const int* in_sizes, int n_in,
                              void* d_out, int out_size, void* d_ws, size_t ws_size,
                              hipStream_t stream)
{
    (void)in_sizes; (void)n_in; (void)out_size; (void)ws_size;
    const float* x   = (const float*)d_in[0];
    const float* Wq  = (const float*)d_in[1];
    const float* Wk  = (const float*)d_in[2];
    const float* Wv  = (const float*)d_in[3];
    const float* Wo  = (const float*)d_in[4];
    const float* bo  = (const float*)d_in[5];
    const float* W1  = (const float*)d_in[6];
    const float* b1  = (const float*)d_in[7];
    const float* W2  = (const float*)d_in[8];
    const float* b2  = (const float*)d_in[9];
    const float* g1  = (const float*)d_in[10];
    const float* be1 = (const float*)d_in[11];
    const float* g2  = (const float*)d_in[12];
    const float* be2 = (const float*)d_in[13];

    char* ws = (char*)d_ws;
    u16*   WqkvT = (u16*)(ws + 0);
    u16*   WoT   = (u16*)(ws + 1572864);
    u16*   W1T   = (u16*)(ws + 2097152);
    u16*   W2T   = (u16*)(ws + 4194304);
    u16*   H     = (u16*)(ws + 6291456);    // ln1/ln2 out [8192][512] bf16
    u16*   PART  = (u16*)(ws + 6291456);    // attn partials (reuses dead H+X2 region)
    float* X2    = (float*)(ws + 14680064); // post-attention residual (f32)
    u16*   QKV   = (u16*)(ws + 31457280);   // [8192][1536]
    u16*   VT    = (u16*)(ws + 56623104);   // [1024][4096]
    u16*   ATT   = (u16*)(ws + 65011712);   // [8192][512]
    u16*   F1    = (u16*)(ws + 31457280);   // [8192][2048], reuses QKV+VT

    prep_w<<<dim3(64, 64, 6), 256, 0, stream>>>(Wq, Wk, Wv, Wo, W1, W2,
                                                WqkvT, WoT, W1T, W2T);
    ln_rows<<<2048, 256, 0, stream>>>(x, g1, be1, H);
    gemm_bt<0><<<dim3(12, 64), 256, 0, stream>>>(H, WqkvT, 1536, 512,
                                                 nullptr, nullptr, QKV);
    transpose_v<<<dim3(128, 16, 2), 256, 0, stream>>>(QKV, VT);
    attn_fwd<<<dim3(160, 16), 256, 0, stream>>>(QKV, VT, PART);
    attn_merge<<<dim3(64, 16), 256, 0, stream>>>(PART, ATT);
    gemm_bt<11><<<dim3(4, 64), 256, 0, stream>>>(ATT, WoT, 512, 512,
                                                 bo, x, X2);
    ln_rows<<<2048, 256, 0, stream>>>(X2, g2, be2, H);
    gemm_bt<5><<<dim3(16, 64), 256, 0, stream>>>(H, W1T, 2048, 512,
                                                 b1, nullptr, F1);
    gemm_bt<11><<<dim3(4, 64), 256, 0, stream>>>(F1, W2T, 512, 2048,
                                                 b2, X2, (float*)d_out);
}

// Round 4
// 232.162 us; speedup vs baseline: 2.0010x; 1.0078x over previous
//
#include <hip/hip_runtime.h>

typedef __attribute__((ext_vector_type(8))) __bf16 bf16x8;
typedef __attribute__((ext_vector_type(4))) __bf16 bf16x4;
typedef __attribute__((ext_vector_type(4))) float f32x4;
typedef __attribute__((ext_vector_type(4))) unsigned int u32x4;
typedef __attribute__((ext_vector_type(4))) unsigned short u16x4;
typedef __attribute__((ext_vector_type(8))) unsigned short u16x8;
typedef __attribute__((ext_vector_type(4))) short s16x4;
typedef unsigned short u16;

static __device__ __forceinline__ u16 f2b(float f) {
    unsigned u = __builtin_bit_cast(unsigned, f);
    u = (u + 0x7FFFu + ((u >> 16) & 1u)) >> 16;
    return (u16)u;
}
static __device__ __forceinline__ float b2f(u16 u) {
    return __builtin_bit_cast(float, ((unsigned)u) << 16);
}
static __device__ __forceinline__ float fexp2(float x) {
#if __has_builtin(__builtin_amdgcn_exp2f)
    return __builtin_amdgcn_exp2f(x);
#else
    return exp2f(x);
#endif
}
static __device__ __forceinline__ f32x4 mfma16(bf16x4 a, bf16x4 b, f32x4 c) {
#if __has_builtin(__builtin_amdgcn_mfma_f32_16x16x16_bf16)
    return __builtin_amdgcn_mfma_f32_16x16x16_bf16(a, b, c, 0, 0, 0);
#else
    return __builtin_amdgcn_mfma_f32_16x16x16bf16_1k(
        __builtin_bit_cast(s16x4, a), __builtin_bit_cast(s16x4, b), c, 0, 0, 0);
#endif
}

// async global->LDS, 16B per lane; LDS dest = wave-uniform base + lane*16
static __device__ __forceinline__ void gload16(const u16* g, u16* l) {
    __builtin_amdgcn_global_load_lds(
        (const __attribute__((address_space(1))) unsigned int*)g,
        (__attribute__((address_space(3))) unsigned int*)l, 16, 0, 0);
}

// ---------------- weight transpose+convert: src[K][N] f32 -> dst[N][K] bf16 ----
__global__ __launch_bounds__(256) void prep_w(
    const float* __restrict__ Wq, const float* __restrict__ Wk,
    const float* __restrict__ Wv, const float* __restrict__ Wo,
    const float* __restrict__ W1, const float* __restrict__ W2,
    u16* __restrict__ WqkvT, u16* __restrict__ WoT,
    u16* __restrict__ W1T, u16* __restrict__ W2T)
{
    const int z = blockIdx.z;
    const float* src; u16* dst; int K, N;
    if (z == 0)      { src = Wq; dst = WqkvT;             K = 512;  N = 512;  }
    else if (z == 1) { src = Wk; dst = WqkvT + 512*512;   K = 512;  N = 512;  }
    else if (z == 2) { src = Wv; dst = WqkvT + 1024*512;  K = 512;  N = 512;  }
    else if (z == 3) { src = Wo; dst = WoT;               K = 512;  N = 512;  }
    else if (z == 4) { src = W1; dst = W1T;               K = 512;  N = 2048; }
    else             { src = W2; dst = W2T;               K = 2048; N = 512;  }
    const int nt = blockIdx.x * 32, kt = blockIdx.y * 32;
    if (nt >= N || kt >= K) return;
    __shared__ float tile[32][33];
    const int tx = threadIdx.x & 31, ty = threadIdx.x >> 5;
    #pragma unroll
    for (int i = 0; i < 4; ++i)
        tile[ty + i*8][tx] = src[(size_t)(kt + ty + i*8) * N + nt + tx];
    __syncthreads();
    #pragma unroll
    for (int i = 0; i < 4; ++i)
        dst[(size_t)(nt + ty + i*8) * K + kt + tx] = f2b(tile[tx][ty + i*8]);
}

// ---------------- LayerNorm rows: [8192][512] f32 -> bf16 ----------------------
__global__ __launch_bounds__(256) void ln_rows(
    const float* __restrict__ x, const float* __restrict__ g,
    const float* __restrict__ b, u16* __restrict__ out)
{
    const int row = blockIdx.x * 4 + (threadIdx.x >> 6);
    const int lane = threadIdx.x & 63;
    const float* xr = x + (size_t)row * 512;
    f32x4 v0 = *(const f32x4*)(xr + lane * 4);
    f32x4 v1 = *(const f32x4*)(xr + 256 + lane * 4);
    float s = v0[0]+v0[1]+v0[2]+v0[3]+v1[0]+v1[1]+v1[2]+v1[3];
    #pragma unroll
    for (int o = 1; o < 64; o <<= 1) s += __shfl_xor(s, o);
    const float mu = s * (1.0f / 512.0f);
    float s2 = 0.f;
    #pragma unroll
    for (int i = 0; i < 4; ++i) { float d0 = v0[i]-mu, d1 = v1[i]-mu; s2 += d0*d0 + d1*d1; }
    #pragma unroll
    for (int o = 1; o < 64; o <<= 1) s2 += __shfl_xor(s2, o);
    const float inv = rsqrtf(s2 * (1.0f/512.0f) + 1e-5f);
    f32x4 g0 = *(const f32x4*)(g + lane*4), g1 = *(const f32x4*)(g + 256 + lane*4);
    f32x4 b0 = *(const f32x4*)(b + lane*4), b1 = *(const f32x4*)(b + 256 + lane*4);
    u16x4 p0, p1;
    #pragma unroll
    for (int i = 0; i < 4; ++i) {
        p0[i] = f2b((v0[i]-mu)*inv*g0[i] + b0[i]);
        p1[i] = f2b((v1[i]-mu)*inv*g1[i] + b1[i]);
    }
    u16* orow = out + (size_t)row * 512;
    *(u16x4*)(orow + lane*4)       = p0;
    *(u16x4*)(orow + 256 + lane*4) = p1;
}

// ---------------- GEMM: C[M][N] = A[M][K](bf16) * BT[N][K](bf16)^T + epilogue --
// FLAGS: 1=bias, 2=residual(f32), 4=relu, 8=store f32 (else bf16),
//        16=scale cols<512 by 512^-0.5*log2(e)  (Q pre-scale for exp2 softmax)
template<int FLAGS>
__global__ __launch_bounds__(256) void gemm_bt(
    const u16* __restrict__ A, const u16* __restrict__ BT,
    const int N, const int K,
    const float* __restrict__ bias, const float* __restrict__ res,
    void* __restrict__ outv)
{
    __shared__ __attribute__((aligned(16))) u16 As[128*32];
    __shared__ __attribute__((aligned(16))) u16 Bs[128*32];
    const int tid = threadIdx.x, lane = tid & 63, w = tid >> 6;
    const int wr = w >> 1, wc = w & 1;
    const int m0 = blockIdx.y << 7, n0 = blockIdx.x << 7;
    const int g = lane >> 4, c = lane & 15;
    const f32x4 fz = {0.f, 0.f, 0.f, 0.f};

    f32x4 acc[4][4];
    #pragma unroll
    for (int m = 0; m < 4; ++m)
      #pragma unroll
      for (int n = 0; n < 4; ++n) acc[m][n] = fz;

    const int srow = tid >> 2;
    const int scs = (((tid & 3) ^ (srow & 3)) * 8);
    const u16* Ag = A  + (size_t)(m0 + srow)*K + scs;
    const u16* Bg = BT + (size_t)(n0 + srow)*K + scs;
    const size_t rstep = (size_t)64 * K;
    u16* AsW = As + w*512;
    u16* BsW = Bs + w*512;

    const int nkt = K >> 5;
    for (int kt = 0; kt < nkt; ++kt) {
        const int k0 = kt << 5;
        gload16(Ag + k0,         AsW);
        gload16(Ag + rstep + k0, AsW + 2048);
        gload16(Bg + k0,         BsW);
        gload16(Bg + rstep + k0, BsW + 2048);
        __syncthreads();
        bf16x8 af[4], bfr[4];
        #pragma unroll
        for (int m = 0; m < 4; ++m) {
            const int row = wr*64 + m*16 + c;
            af[m] = *(const bf16x8*)(As + row*32 + (((g*16) ^ ((row&3)<<4)) >> 1));
        }
        #pragma unroll
        for (int n = 0; n < 4; ++n) {
            const int row = wc*64 + n*16 + c;
            bfr[n] = *(const bf16x8*)(Bs + row*32 + (((g*16) ^ ((row&3)<<4)) >> 1));
        }
        #pragma unroll
        for (int m = 0; m < 4; ++m)
          #pragma unroll
          for (int n = 0; n < 4; ++n)
            acc[m][n] = __builtin_amdgcn_mfma_f32_16x16x32_bf16(af[m], bfr[n], acc[m][n], 0, 0, 0);
        __syncthreads();
    }

    #pragma unroll
    for (int m = 0; m < 4; ++m) {
        const int row = m0 + wr*64 + m*16 + 4*g;
        #pragma unroll
        for (int n = 0; n < 4; ++n) {
            const int col = n0 + wc*64 + n*16 + c;
            const float bv = (FLAGS & 1) ? bias[col] : 0.0f;
            const float qs = (FLAGS & 16) ? ((col < 512) ? 0.0637587246f : 1.0f) : 1.0f;
            #pragma unroll
            for (int r = 0; r < 4; ++r) {
                float v = acc[m][n][r] + bv;
                if (FLAGS & 16) v *= qs;
                if (FLAGS & 2) v += res[(size_t)(row + r)*N + col];
                if (FLAGS & 4) v = fmaxf(v, 0.0f);
                if (FLAGS & 8) ((float*)outv)[(size_t)(row + r)*N + col] = v;
                else           ((u16*)outv)[(size_t)(row + r)*N + col] = f2b(v);
            }
        }
    }
}

// ---------------- V transpose: qkv cols [1024..1536) -> vT[B*H*64][4096] ------
__global__ __launch_bounds__(256) void transpose_v(
    const u16* __restrict__ qkv, u16* __restrict__ vT)
{
    const int b = blockIdx.z;
    const int t0 = blockIdx.x * 32, c0 = blockIdx.y * 32;
    __shared__ u16 tile[32][33];
    const int tx = threadIdx.x & 31, ty = threadIdx.x >> 5;
    #pragma unroll
    for (int i = 0; i < 4; ++i)
        tile[ty + i*8][tx] =
            qkv[(size_t)(b*4096 + t0 + ty + i*8)*1536 + 1024 + c0 + tx];
    __syncthreads();
    #pragma unroll
    for (int i = 0; i < 4; ++i)
        vT[(size_t)(b*512 + c0 + ty + i*8)*4096 + t0 + tx] = tile[tx][ty + i*8];
}

// ---------------- causal flash attention, split-kv, static max, kv-split waves -
// grid (160, B*H); 4 waves; per 64-kv tile, wave w owns strip kv [64t+16w, +16).
// S^T = mfma32(A=K_strip, B=Q): lane holds P^T[kv=4g+r][q=sub*16+c16] -> directly
// the B-frag of mfma16(A=V^T, B=P^T) -> O^T accumulated per wave, cross-wave
// LDS reduce once per chunk. Q pre-scaled by 512^-0.5*log2(e) -> softmax = exp2.
__global__ __launch_bounds__(256) void attn_fwd(
    const u16* __restrict__ qkv, const u16* __restrict__ vT, u16* __restrict__ part)
{
    const int bh = blockIdx.y, b = bh >> 3, h = bh & 7;
    const int i = blockIdx.x;
    int qt, cch;
    if (i < 16)      { qt = i;                        cch = 0; }
    else if (i < 48) { int j = i-16; qt = 16 + (j>>1); cch = j & 1; }
    else if (i < 96) { int j = i-48; int d = j/3; qt = 32 + d; cch = j - 3*d; }
    else             { int j = i-96; qt = 48 + (j>>2); cch = j & 3; }
    const int t0 = cch*16;
    const int t1e = t0 + 16, t1 = (t1e < qt+1) ? t1e : qt+1;

    const int tid = threadIdx.x, lane = tid & 63, w = tid >> 6;
    const int g = lane >> 4, c16 = lane & 15;
    // [0,8KB) K bufs x2, [16KB,32KB) V bufs x2; reduce: 2 f32 images + lbuf
    __shared__ __attribute__((aligned(16))) u16 smem[16896];
    u16* Ks0 = smem;          u16* Ks1 = smem + 4096;
    u16* Vs0 = smem + 8192;   u16* Vs1 = smem + 12288;

    const u16* qp  = qkv + (size_t)b*4096*1536 + h*64;
    const u16* kp  = qp + 512;
    const u16* vtp = vT + (size_t)bh*64*4096;

    // DMA staging: row = tid>>3 (call2 +32), src chunk = (tid&7) ^ (row&7)
    const int srow = tid >> 3;
    const int scs  = (((tid & 7) ^ (srow & 7)) * 8);
    const u16* kg0 = kp + (size_t)srow*1536 + scs;
    const u16* kg1 = kg0 + (size_t)32*1536;
    const u16* vg0 = vtp + (size_t)srow*4096 + scs;
    const u16* vg1 = vg0 + (size_t)32*4096;
    u16* KsW0 = Ks0 + w*512;  u16* VsW0 = Vs0 + w*512;
    u16* KsW1 = Ks1 + w*512;  u16* VsW1 = Vs1 + w*512;

    const int Q0 = qt*64;
    // Q B-fragments [sub][h]: lane -> Q[Q0+sub*16+c16][h*32+g*8 ..+8]
    bf16x8 qB[4][2];
    #pragma unroll
    for (int sub = 0; sub < 4; ++sub) {
        const u16* qr = qp + (size_t)(Q0 + sub*16 + c16)*1536 + g*8;
        qB[sub][0] = *(const bf16x8*)(qr);
        qB[sub][1] = *(const bf16x8*)(qr + 32);
    }

    const f32x4 fz = {0.f,0.f,0.f,0.f};
    f32x4 oacc[4][4];   // [dt][sub]: O^T[d=dt*16+4g+r][q=sub*16+c16]
    #pragma unroll
    for (int dt = 0; dt < 4; ++dt)
      #pragma unroll
      for (int sub = 0; sub < 4; ++sub) oacc[dt][sub] = fz;
    float lsum[4] = {0.f, 0.f, 0.f, 0.f};

    // LDS read offsets (elements)
    const int kRow  = 16*w + c16;
    const int kOff0 = kRow*64 + ((g    ) ^ (c16 & 7))*8;
    const int kOff1 = kRow*64 + ((4 + g) ^ (c16 & 7))*8;
    const int vChk  = ((2*w + (g >> 1)) ^ (c16 & 7))*8 + (g & 1)*4;

    // prologue: stage tile t0 into buf 0
    {
        const size_t kvo = (size_t)(t0 << 6);
        gload16(kg0 + kvo*1536, KsW0); gload16(kg1 + kvo*1536, KsW0 + 2048);
        gload16(vg0 + kvo,      VsW0); gload16(vg1 + kvo,      VsW0 + 2048);
    }
    __syncthreads();

    int buf = 0;
    for (int t = t0; t < t1; ++t) {
        if (t + 1 < t1) {
            const size_t kvo = (size_t)((t+1) << 6);
            u16* kd = buf ? KsW0 : KsW1;
            u16* vd = buf ? VsW0 : VsW1;
            gload16(kg0 + kvo*1536, kd); gload16(kg1 + kvo*1536, kd + 2048);
            gload16(vg0 + kvo,      vd); gload16(vg1 + kvo,      vd + 2048);
        }
        const u16* Kb = buf ? Ks1 : Ks0;
        const u16* Vb = buf ? Vs1 : Vs0;

        // ---- S^T[kv_strip][64 q] = K_strip . Q^T ----
        const bf16x8 kA0 = *(const bf16x8*)(Kb + kOff0);
        const bf16x8 kA1 = *(const bf16x8*)(Kb + kOff1);
        f32x4 s[4];
        #pragma unroll
        for (int sub = 0; sub < 4; ++sub) {
            f32x4 sv = __builtin_amdgcn_mfma_f32_16x16x32_bf16(kA0, qB[sub][0], fz, 0, 0, 0);
            s[sub]   = __builtin_amdgcn_mfma_f32_16x16x32_bf16(kA1, qB[sub][1], sv, 0, 0, 0);
        }
        // ---- V^T A-fragments ----
        bf16x4 va[4];
        #pragma unroll
        for (int dt = 0; dt < 4; ++dt)
            va[dt] = *(const bf16x4*)(Vb + (dt*16 + c16)*64 + vChk);
        // ---- softmax numerator (exp2, static max 0), in-register P^T ----
        bf16x4 pt[4];
        if (t < qt) {
            #pragma unroll
            for (int sub = 0; sub < 4; ++sub) {
                float p0 = fexp2(s[sub][0]), p1 = fexp2(s[sub][1]);
                float p2 = fexp2(s[sub][2]), p3 = fexp2(s[sub][3]);
                lsum[sub] += (p0 + p1) + (p2 + p3);
                bf16x4 pv;
                pv[0] = (__bf16)p0; pv[1] = (__bf16)p1;
                pv[2] = (__bf16)p2; pv[3] = (__bf16)p3;
                pt[sub] = pv;
            }
        } else {  // diagonal tile: causal mask
            const int kvbase = t*64 + 16*w + 4*g;
            #pragma unroll
            for (int sub = 0; sub < 4; ++sub) {
                const int qi = Q0 + sub*16 + c16;
                bf16x4 pv; float a = 0.f;
                #pragma unroll
                for (int r = 0; r < 4; ++r) {
                    float p = (kvbase + r <= qi) ? fexp2(s[sub][r]) : 0.0f;
                    a += p; pv[r] = (__bf16)p;
                }
                lsum[sub] += a; pt[sub] = pv;
            }
        }
        // ---- O^T += V^T . P^T ----
        #pragma unroll
        for (int dt = 0; dt < 4; ++dt)
          #pragma unroll
          for (int sub = 0; sub < 4; ++sub)
            oacc[dt][sub] = mfma16(va[dt], pt[sub], oacc[dt][sub]);
        __syncthreads();
        buf ^= 1;
    }

    // l: reduce across g-groups (kv within strip)
    #pragma unroll
    for (int sub = 0; sub < 4; ++sub) {
        float v = lsum[sub];
        v += __shfl_xor(v, 16);
        v += __shfl_xor(v, 32);
        lsum[sub] = v;
    }

    // ---- cross-wave reduction (LDS reuse; loop ended with barrier) ----
    float* red  = (float*)smem;            // 2 images x 4096 f32 ([q][d], 16B-chunk XOR c16)
    float* lbuf = (float*)smem + 8192;     // [4 waves][64 q]
    if (g == 0) {
        #pragma unroll
        for (int sub = 0; sub < 4; ++sub) lbuf[w*64 + sub*16 + c16] = lsum[sub];
    }
    if (w >= 2) {
        float* img = red + (w & 1)*4096;
        #pragma unroll
        for (int sub = 0; sub < 4; ++sub) {
            const int ro = (sub*16 + c16)*64;
            #pragma unroll
            for (int dt = 0; dt < 4; ++dt)
                *(f32x4*)(img + ro + ((dt*4 + g) ^ c16)*4) = oacc[dt][sub];
        }
    }
    __syncthreads();
    if (w < 2) {
        float* img = red + w*4096;
        #pragma unroll
        for (int sub = 0; sub < 4; ++sub) {
            const int ro = (sub*16 + c16)*64;
            #pragma unroll
            for (int dt = 0; dt < 4; ++dt)
                oacc[dt][sub] += *(const f32x4*)(img + ro + ((dt*4 + g) ^ c16)*4);
        }
    }
    __syncthreads();
    if (w == 1) {
        #pragma unroll
        for (int sub = 0; sub < 4; ++sub) {
            const int ro = (sub*16 + c16)*64;
            #pragma unroll
            for (int dt = 0; dt < 4; ++dt)
                *(f32x4*)(red + ro + ((dt*4 + g) ^ c16)*4) = oacc[dt][sub];
        }
    }
    __syncthreads();
    if (w == 0) {
        u16* onum = part + (size_t)(bh*160 + i) * 4224;   // 8448 B/slot
        float* lout = (float*)(onum + 4096);
        #pragma unroll
        for (int sub = 0; sub < 4; ++sub) {
            const int qrow = sub*16 + c16;
            const int ro = qrow*64;
            #pragma unroll
            for (int dt = 0; dt < 4; ++dt) {
                f32x4 o = oacc[dt][sub] + *(const f32x4*)(red + ro + ((dt*4 + g) ^ c16)*4);
                bf16x4 ov;
                ov[0] = (__bf16)o[0]; ov[1] = (__bf16)o[1];
                ov[2] = (__bf16)o[2]; ov[3] = (__bf16)o[3];
                *(u16x4*)(onum + qrow*64 + dt*16 + 4*g) = __builtin_bit_cast(u16x4, ov);
            }
            if (g == 0)
                lout[qrow] = lbuf[qrow] + lbuf[64 + qrow] + lbuf[128 + qrow] + lbuf[192 + qrow];
        }
    }
}

// ---------------- merge split-kv partials, normalize, write ATT ---------------
__global__ __launch_bounds__(256) void attn_merge(
    const u16* __restrict__ part, u16* __restrict__ att)
{
    const int q = blockIdx.x, bh = blockIdx.y, b = bh >> 3, h = bh & 7;
    int start, n;
    if (q < 16)      { start = q;               n = 1; }
    else if (q < 32) { start = 16 + 2*(q-16);   n = 2; }
    else if (q < 48) { start = 48 + 3*(q-32);   n = 3; }
    else             { start = 96 + 4*(q-48);   n = 4; }
    const int t = threadIdx.x;
    const int row = t >> 2, c0 = (t & 3) * 16;
    float acc[16];
    #pragma unroll
    for (int j = 0; j < 16; ++j) acc[j] = 0.f;
    float lt = 0.f;
    const u16* p0 = part + (size_t)(bh*160 + start) * 4224;
    for (int ci = 0; ci < n; ++ci) {
        const u16* pc = p0 + (size_t)ci * 4224;
        lt += ((const float*)(pc + 4096))[row];
        u16x8 a = *(const u16x8*)(pc + row*64 + c0);
        u16x8 bq = *(const u16x8*)(pc + row*64 + c0 + 8);
        #pragma unroll
        for (int j = 0; j < 8; ++j) { acc[j] += b2f(a[j]); acc[8+j] += b2f(bq[j]); }
    }
    const float inv = 1.0f / lt;
    u16x8 o1, o2;
    #pragma unroll
    for (int j = 0; j < 8; ++j) { o1[j] = f2b(acc[j]*inv); o2[j] = f2b(acc[8+j]*inv); }
    u16* dst = att + (size_t)(b*4096 + q*64 + row)*512 + h*64 + c0;
    *(u16x8*)dst = o1;
    *(u16x8*)(dst + 8) = o2;
}

// -------------------------------------------------------------------------------
extern "C" void kernel_launch(void* const* d_in, const int* in_sizes, int n_in,
                              void* d_out, int out_size, void* d_ws, size_t ws_size,
                              hipStream_t stream)
{
    (void)in_sizes; (void)n_in; (void)out_size; (void)ws_size;
    const float* x   = (const float*)d_in[0];
    const float* Wq  = (const float*)d_in[1];
    const float* Wk  = (const float*)d_in[2];
    const float* Wv  = (const float*)d_in[3];
    const float* Wo  = (const float*)d_in[4];
    const float* bo  = (const float*)d_in[5];
    const float* W1  = (const float*)d_in[6];
    const float* b1  = (const float*)d_in[7];
    const float* W2  = (const float*)d_in[8];
    const float* b2  = (const float*)d_in[9];
    const float* g1  = (const float*)d_in[10];
    const float* be1 = (const float*)d_in[11];
    const float* g2  = (const float*)d_in[12];
    const float* be2 = (const float*)d_in[13];

    char* ws = (char*)d_ws;
    u16*   WqkvT = (u16*)(ws + 0);
    u16*   WoT   = (u16*)(ws + 1572864);
    u16*   W1T   = (u16*)(ws + 2097152);
    u16*   W2T   = (u16*)(ws + 4194304);
    u16*   H     = (u16*)(ws + 6291456);    // ln1/ln2 out [8192][512] bf16
    u16*   PART  = (u16*)(ws + 6291456);    // attn partials (reuses dead H+X2 region)
    float* X2    = (float*)(ws + 14680064); // post-attention residual (f32)
    u16*   QKV   = (u16*)(ws + 31457280);   // [8192][1536]
    u16*   VT    = (u16*)(ws + 56623104);   // [1024][4096]
    u16*   ATT   = (u16*)(ws + 65011712);   // [8192][512]
    u16*   F1    = (u16*)(ws + 31457280);   // [8192][2048], reuses QKV+VT

    prep_w<<<dim3(64, 64, 6), 256, 0, stream>>>(Wq, Wk, Wv, Wo, W1, W2,
                                                WqkvT, WoT, W1T, W2T);
    ln_rows<<<2048, 256, 0, stream>>>(x, g1, be1, H);
    gemm_bt<16><<<dim3(12, 64), 256, 0, stream>>>(H, WqkvT, 1536, 512,
                                                  nullptr, nullptr, QKV);
    transpose_v<<<dim3(128, 16, 2), 256, 0, stream>>>(QKV, VT);
    attn_fwd<<<dim3(160, 16), 256, 0, stream>>>(QKV, VT, PART);
    attn_merge<<<dim3(64, 16), 256, 0, stream>>>(PART, ATT);
    gemm_bt<11><<<dim3(4, 64), 256, 0, stream>>>(ATT, WoT, 512, 512,
                                                 bo, x, X2);
    ln_rows<<<2048, 256, 0, stream>>>(X2, g2, be2, H);
    gemm_bt<5><<<dim3(16, 64), 256, 0, stream>>>(H, W1T, 2048, 512,
                                                 b1, nullptr, F1);
    gemm_bt<11><<<dim3(4, 64), 256, 0, stream>>>(F1, W2T, 512, 2048,
                                                 b2, X2, (float*)d_out);
}